// Round 19
// baseline (974.952 us; speedup 1.0000x reference)
//
#include <hip/hip_runtime.h>
#include <hip/hip_bf16.h>
#include <math.h>

// ---------------- problem constants ----------------
#define NN 30000
#define EE 480000
#define ET (EE + NN)   // edges + self loops = 510000
#define NEG_SLOPE 0.2f
#define BN_EPS 1e-5f

struct LayerCfg { int cin, C, H; };
static const LayerCfg g_cfg[5] = {
    {128, 100, 5}, {500, 50, 5}, {250, 32, 4}, {128, 8, 4}, {32, 1, 1}
};

typedef short short8 __attribute__((ext_vector_type(8)));
typedef float f32x4 __attribute__((ext_vector_type(4)));

__device__ __forceinline__ unsigned short f2bf(float f) {
    unsigned int u = __builtin_bit_cast(unsigned int, f);
    u = (u + 0x7FFFu + ((u >> 16) & 1u)) >> 16;
    return (unsigned short)u;
}
__device__ __forceinline__ float bf2f(unsigned short h) {
    unsigned int u = ((unsigned int)h) << 16;
    return __builtin_bit_cast(float, u);
}

// ---------------- graph / CSR kernels ----------------

// standalone edge-weight sum (LDS reduce, 1 atomic per block)
__global__ void ewsum_kernel(const float* __restrict__ ew, float* __restrict__ out) {
    __shared__ float sdata[256];
    int tid = threadIdx.x;
    float s = 0.f;
    for (int i = blockIdx.x * blockDim.x + tid; i < EE; i += gridDim.x * blockDim.x)
        s += ew[i];
    sdata[tid] = s;
    __syncthreads();
    for (int off = 128; off > 0; off >>= 1) {
        if (tid < off) sdata[tid] += sdata[tid + off];
        __syncthreads();
    }
    if (tid == 0) atomicAdd(out, sdata[0]);
}

// per-edge rank via ONE atomic histogram pass (~85us scattered-RMW floor)
__global__ void build_edges_kernel(const int* __restrict__ ei,
                                   int* __restrict__ rank, int* __restrict__ cnt) {
    int e = blockIdx.x * blockDim.x + threadIdx.x;
    if (e >= ET) return;
    int d = (e < EE) ? ei[EE + e] : (e - EE);
    rank[e] = atomicAdd(&cnt[d], 1);
}

// exclusive prefix over cnt -> off; log-step scan over the 1024 partials
__global__ void scan_kernel(const int* __restrict__ cnt, int* __restrict__ off) {
    __shared__ int lsum[1024];
    const int T = 1024;
    int t = threadIdx.x;
    int chunk = (NN + T - 1) / T;
    int base = t * chunk;
    int end = min(NN, base + chunk);
    int s = 0;
    for (int i = base; i < end; i++) s += cnt[i];
    lsum[t] = s;
    __syncthreads();
    // Hillis-Steele inclusive scan, then shift to exclusive
    for (int d = 1; d < T; d <<= 1) {
        int v = (t >= d) ? lsum[t - d] : 0;
        __syncthreads();
        lsum[t] += v;
        __syncthreads();
    }
    int run = (t == 0) ? 0 : lsum[t - 1];
    for (int i = base; i < end; i++) {
        off[i] = run;
        run += cnt[i];
    }
    if (t == 0) off[NN] = ET;
}

// scatter edges to CSR order via precomputed rank — NO atomics; src/dst from ei
__global__ void fill_kernel(const int* __restrict__ ei, const int* __restrict__ rank,
                            const float* __restrict__ ew, const float* __restrict__ esum,
                            const int* __restrict__ off,
                            int* __restrict__ csr_src, float* __restrict__ csr_ea) {
    int e = blockIdx.x * blockDim.x + threadIdx.x;
    if (e >= ET) return;
    int sv, d;
    if (e < EE) { sv = ei[e]; d = ei[EE + e]; }
    else        { sv = e - EE; d = e - EE; }
    int p = off[d] + rank[e];
    csr_src[p] = sv;
    csr_ea[p]  = (e < EE) ? ew[e] : esum[0] * (1.0f / (float)EE);
}

// ---------------- all-layer weight prep (transpose + wedot fused) ----------------

struct PrepArgs {
    const float* W[5];
    const float* We[5];
    const float* ae[5];
    unsigned short* bh[5];
    unsigned short* bl[5];
    float* wedot;            // out: [5][8]
    int K[5], N[5], Kp[5], Np[5], C[5], H[5];
};

__global__ void transpose_all_kernel(PrepArgs a) {
    int l = blockIdx.z;
    if (blockIdx.x == 0 && blockIdx.y == 0 && threadIdx.y == 0 && threadIdx.x < 8) {
        int hd = threadIdx.x;
        if (hd < a.H[l]) {
            int C = a.C[l];
            const float* We = a.We[l] + hd * C;
            const float* ae = a.ae[l] + hd * C;
            float s = 0.f;
            for (int c = 0; c < C; c++) s += We[c] * ae[c];
            a.wedot[l * 8 + hd] = s;
        }
    }
    int Kp = a.Kp[l], Np = a.Np[l], K = a.K[l], N = a.N[l];
    int kb = blockIdx.x * 32, nb = blockIdx.y * 32;
    if (kb >= Kp || nb >= Np) return;
    const float* B = a.W[l];
    unsigned short* Bth = a.bh[l];
    unsigned short* Btl = a.bl[l];
    __shared__ float tile[32][33];
    int tx = threadIdx.x, ty = threadIdx.y;   // 32 x 8
#pragma unroll
    for (int i = 0; i < 4; i++) {
        int k = kb + ty + i * 8, n = nb + tx;
        tile[ty + i * 8][tx] = (k < K && n < N) ? B[(size_t)k * N + n] : 0.f;
    }
    __syncthreads();
#pragma unroll
    for (int i = 0; i < 4; i++) {
        int n = nb + ty + i * 8, k = kb + tx;
        if (n < Np && k < Kp) {
            float v = tile[tx][ty + i * 8];
            unsigned short hi = f2bf(v);
            unsigned short lo = f2bf(v - bf2f(hi));
            size_t idx = (size_t)n * Kp + k;
            Bth[idx] = hi;
            Btl[idx] = lo;
        }
    }
}

// ---------------- split-bf16 MFMA GEMM with optional fused BN+ReLU on A ----------------
#define GBM 128
#define GBNT 128
#define GBK 32
#define ASTR 36
__global__ __launch_bounds__(256) void gemm_split_kernel(const float* __restrict__ A,
                                                         const unsigned short* __restrict__ Bt_hi,
                                                         const unsigned short* __restrict__ Bt_lo,
                                                         float* __restrict__ Cm,
                                                         unsigned short* __restrict__ Ch16,
                                                         int M, int Kp, int Nc,
                                                         const float* __restrict__ colsum,
                                                         const float* __restrict__ colsumsq,
                                                         const float* __restrict__ g,
                                                         const float* __restrict__ beta,
                                                         int D) {
    __shared__ short AsH[GBM * ASTR];
    __shared__ short AsL[GBM * ASTR];
    __shared__ short BsH[GBNT * ASTR];
    __shared__ short BsL[GBNT * ASTR];
    __shared__ float sscale[512];
    __shared__ float sshift[512];
    int tid = threadIdx.x;
    bool bn = (colsum != nullptr);
    if (bn) {
        for (int c = tid; c < Kp; c += 256) {
            float sc = 0.f, sh = 0.f;
            if (c < D) {
                float mu = colsum[c] * (1.0f / (float)NN);
                float var = colsumsq[c] * (1.0f / (float)NN) - mu * mu;
                sc = g[c] * rsqrtf(var + BN_EPS);
                sh = beta[c] - mu * sc;
            }
            sscale[c] = sc;
            sshift[c] = sh;
        }
        __syncthreads();
    }
    int wave = tid >> 6, lane = tid & 63;
    int q = lane >> 4, r = lane & 15;
    int m0 = blockIdx.y * GBM, n0 = blockIdx.x * GBNT;
    int wm = (wave & 1) * 64, wn = (wave >> 1) * 64;
    f32x4 acc[4][4];
#pragma unroll
    for (int i = 0; i < 4; i++)
#pragma unroll
        for (int j = 0; j < 4; j++) acc[i][j] = (f32x4)(0.f);

    int arow2 = tid >> 1;
    int acol2 = (tid & 1) * 16;
    int brow = tid >> 2;
    int bcol = (tid & 3) * 8;

    int ksteps = Kp / GBK;
    for (int ks = 0; ks < ksteps; ks++) {
        int k0 = ks * GBK;
        {
            int m = m0 + arow2;
            float v[16];
            if (m < M) {
                const float* Ap = A + (size_t)m * Kp + k0 + acol2;
                float4 f0 = *(const float4*)(Ap);
                float4 f1 = *(const float4*)(Ap + 4);
                float4 f2 = *(const float4*)(Ap + 8);
                float4 f3 = *(const float4*)(Ap + 12);
                v[0]=f0.x; v[1]=f0.y; v[2]=f0.z; v[3]=f0.w;
                v[4]=f1.x; v[5]=f1.y; v[6]=f1.z; v[7]=f1.w;
                v[8]=f2.x; v[9]=f2.y; v[10]=f2.z; v[11]=f2.w;
                v[12]=f3.x; v[13]=f3.y; v[14]=f3.z; v[15]=f3.w;
                if (bn) {
                    int cb = k0 + acol2;
#pragma unroll
                    for (int i = 0; i < 16; i++)
                        v[i] = fmaxf(v[i] * sscale[cb + i] + sshift[cb + i], 0.f);
                }
            } else {
#pragma unroll
                for (int i = 0; i < 16; i++) v[i] = 0.f;
            }
#pragma unroll
            for (int i = 0; i < 16; i++) {
                unsigned short hi = f2bf(v[i]);
                unsigned short lo = f2bf(v[i] - bf2f(hi));
                AsH[arow2 * ASTR + acol2 + i] = (short)hi;
                AsL[arow2 * ASTR + acol2 + i] = (short)lo;
            }
        }
#pragma unroll
        for (int p = 0; p < 2; p++) {
            int row = p * 64 + brow;
            size_t gidx = (size_t)(n0 + row) * Kp + k0 + bcol;
            *((uint4*)(BsH + row * ASTR + bcol)) = *((const uint4*)(Bt_hi + gidx));
            *((uint4*)(BsL + row * ASTR + bcol)) = *((const uint4*)(Bt_lo + gidx));
        }
        __syncthreads();
        short8 ah[4], al[4], bh[4], bl[4];
#pragma unroll
        for (int i = 0; i < 4; i++) {
            ah[i] = *((const short8*)(AsH + (wm + i * 16 + r) * ASTR + q * 8));
            al[i] = *((const short8*)(AsL + (wm + i * 16 + r) * ASTR + q * 8));
        }
#pragma unroll
        for (int j = 0; j < 4; j++) {
            bh[j] = *((const short8*)(BsH + (wn + j * 16 + r) * ASTR + q * 8));
            bl[j] = *((const short8*)(BsL + (wn + j * 16 + r) * ASTR + q * 8));
        }
#pragma unroll
        for (int i = 0; i < 4; i++)
#pragma unroll
            for (int j = 0; j < 4; j++) {
                acc[i][j] = __builtin_amdgcn_mfma_f32_16x16x32_bf16(ah[i], bh[j], acc[i][j], 0, 0, 0);
                acc[i][j] = __builtin_amdgcn_mfma_f32_16x16x32_bf16(ah[i], bl[j], acc[i][j], 0, 0, 0);
                acc[i][j] = __builtin_amdgcn_mfma_f32_16x16x32_bf16(al[i], bh[j], acc[i][j], 0, 0, 0);
            }
        __syncthreads();
    }
#pragma unroll
    for (int i = 0; i < 4; i++) {
#pragma unroll
        for (int j = 0; j < 4; j++) {
#pragma unroll
            for (int reg = 0; reg < 4; reg++) {
                int mrow = m0 + wm + i * 16 + q * 4 + reg;
                int ncol = n0 + wn + j * 16 + r;
                if (mrow < M && ncol < Nc) {
                    float val = acc[i][j][reg];
                    if (Cm)   Cm[(size_t)mrow * Nc + ncol] = val;
                    if (Ch16) Ch16[(size_t)mrow * Nc + ncol] = f2bf(val);
                }
            }
        }
    }
}

// layer-5 fused GEMV
__global__ void gemv_l5_kernel(const float* __restrict__ X, const float* __restrict__ W,
                               const float* __restrict__ a_s, const float* __restrict__ a_d,
                               float* __restrict__ h, float* __restrict__ al_src,
                               float* __restrict__ al_dst) {
    __shared__ float w[32];
    if (threadIdx.x < 32) w[threadIdx.x] = W[threadIdx.x];
    __syncthreads();
    int n = blockIdx.x * blockDim.x + threadIdx.x;
    if (n >= NN) return;
    const float* row = X + (size_t)n * 32;
    float s = 0.f;
#pragma unroll
    for (int i = 0; i < 8; i++) {
        float4 f = *(const float4*)(row + i * 4);
        s += f.x * w[i * 4] + f.y * w[i * 4 + 1] + f.z * w[i * 4 + 2] + f.w * w[i * 4 + 3];
    }
    h[n] = s;
    al_src[n] = s * a_s[0];
    al_dst[n] = s * a_d[0];
}

// wave-per-node attention dots, bf16 h (layers 1-4)
__global__ void al_wave_h16_kernel(const unsigned short* __restrict__ h16,
                                   const float* __restrict__ a_s,
                                   const float* __restrict__ a_d,
                                   float* __restrict__ al_src, float* __restrict__ al_dst,
                                   int H, int C, int HC) {
    int w = (blockIdx.x * blockDim.x + threadIdx.x) >> 6;
    int lane = threadIdx.x & 63;
    if (w >= NN) return;
    const unsigned short* row = h16 + (size_t)w * HC;
    float s1[5] = {0.f, 0.f, 0.f, 0.f, 0.f};
    float s2[5] = {0.f, 0.f, 0.f, 0.f, 0.f};
#pragma unroll
    for (int hd = 0; hd < 5; hd++) {
        if (hd >= H) break;
        int base = hd * C;
        for (int c = lane * 2; c < C; c += 128) {
            unsigned int u = *(const unsigned int*)(row + base + c);
            float v0 = bf2f((unsigned short)(u & 0xffffu));
            float v1 = bf2f((unsigned short)(u >> 16));
            s1[hd] += v0 * a_s[base + c] + v1 * a_s[base + c + 1];
            s2[hd] += v0 * a_d[base + c] + v1 * a_d[base + c + 1];
        }
    }
#pragma unroll
    for (int hd = 0; hd < 5; hd++) {
        if (hd >= H) break;
#pragma unroll
        for (int off = 32; off > 0; off >>= 1) {
            s1[hd] += __shfl_xor(s1[hd], off, 64);
            s2[hd] += __shfl_xor(s2[hd], off, 64);
        }
    }
    if (lane == 0) {
#pragma unroll
        for (int hd = 0; hd < 5; hd++) {
            if (hd >= H) break;
            al_src[(size_t)w * H + hd] = s1[hd];
            al_dst[(size_t)w * H + hd] = s2[hd];
        }
    }
}

// fused logit + ONLINE segment softmax; alpha_t[hd*ET + p]
__global__ void attn_kernel(const float* __restrict__ al_src,
                            const float* __restrict__ al_dst,
                            const int* __restrict__ csr_src,
                            const float* __restrict__ csr_ea,
                            const float* __restrict__ we_dot,
                            const int* __restrict__ off,
                            float* __restrict__ alpha_t, int H, int NH) {
    int t = blockIdx.x * blockDim.x + threadIdx.x;
    if (t >= NH) return;
    int n = t / H, hd = t - n * H;
    int s = off[n], e = off[n + 1];
    float ad = al_dst[(size_t)n * H + hd];
    float wd = we_dot[hd];
    float* arow = alpha_t + (size_t)hd * ET;
    float m = -INFINITY, l = 0.f;
    int p = s;
    for (; p + 3 < e; p += 4) {
        int s0 = csr_src[p], s1 = csr_src[p + 1], s2 = csr_src[p + 2], s3 = csr_src[p + 3];
        float w0 = csr_ea[p], w1 = csr_ea[p + 1], w2 = csr_ea[p + 2], w3 = csr_ea[p + 3];
        float l0 = al_src[(size_t)s0 * H + hd] + ad + w0 * wd;
        float l1 = al_src[(size_t)s1 * H + hd] + ad + w1 * wd;
        float l2 = al_src[(size_t)s2 * H + hd] + ad + w2 * wd;
        float l3 = al_src[(size_t)s3 * H + hd] + ad + w3 * wd;
        l0 = (l0 >= 0.f) ? l0 : NEG_SLOPE * l0;
        l1 = (l1 >= 0.f) ? l1 : NEG_SLOPE * l1;
        l2 = (l2 >= 0.f) ? l2 : NEG_SLOPE * l2;
        l3 = (l3 >= 0.f) ? l3 : NEG_SLOPE * l3;
        arow[p] = l0; arow[p + 1] = l1; arow[p + 2] = l2; arow[p + 3] = l3;
        float mq = fmaxf(fmaxf(l0, l1), fmaxf(l2, l3));
        float nm = fmaxf(m, mq);
        l = l * __expf(m - nm)
          + __expf(l0 - nm) + __expf(l1 - nm) + __expf(l2 - nm) + __expf(l3 - nm);
        m = nm;
    }
    for (; p < e; p++) {
        float lg = al_src[(size_t)csr_src[p] * H + hd] + ad + csr_ea[p] * wd;
        lg = (lg >= 0.f) ? lg : NEG_SLOPE * lg;
        arow[p] = lg;
        float nm = fmaxf(m, lg);
        l = l * __expf(m - nm) + __expf(lg - nm);
        m = nm;
    }
    float inv = 1.f / fmaxf(l, 1e-16f);
    for (p = s; p < e; p++) arow[p] = __expf(arow[p] - m) * inv;
}

// bf16 gather aggregate, 4 cols/thread (4|C); optional fused relu; pitched output
__global__ void aggregate_v4h_kernel(const unsigned short* __restrict__ h16,
                                     const float* __restrict__ alpha_t,
                                     const int* __restrict__ off,
                                     const int* __restrict__ csr_src,
                                     const float* __restrict__ bias,
                                     float* __restrict__ out,
                                     int C, int HC, int HC4, int total4, int relu, int opitch) {
    int t = blockIdx.x * blockDim.x + threadIdx.x;
    if (t >= total4) return;
    int n = t / HC4, j4 = t - n * HC4;
    int j = j4 * 4;
    int hd = j / C;
    const float* arow = alpha_t + (size_t)hd * ET;
    int s = off[n], e = off[n + 1];
    float4 acc = make_float4(0.f, 0.f, 0.f, 0.f);
    int p = s;
    for (; p + 3 < e; p += 4) {
        int idx[4]; float a[4];
#pragma unroll
        for (int u = 0; u < 4; u++) { idx[u] = csr_src[p + u]; a[u] = arow[p + u]; }
#pragma unroll
        for (int u = 0; u < 4; u++) {
            ushort4 uv = *(const ushort4*)(h16 + (size_t)idx[u] * HC + j);
            acc.x += a[u] * bf2f(uv.x);
            acc.y += a[u] * bf2f(uv.y);
            acc.z += a[u] * bf2f(uv.z);
            acc.w += a[u] * bf2f(uv.w);
        }
    }
    for (; p < e; p++) {
        int s0 = csr_src[p];
        float a0 = arow[p];
        ushort4 uv = *(const ushort4*)(h16 + (size_t)s0 * HC + j);
        acc.x += a0 * bf2f(uv.x);
        acc.y += a0 * bf2f(uv.y);
        acc.z += a0 * bf2f(uv.z);
        acc.w += a0 * bf2f(uv.w);
    }
    float4 bi = *(const float4*)(bias + j);
    float4 rr = make_float4(acc.x + bi.x, acc.y + bi.y, acc.z + bi.z, acc.w + bi.w);
    if (relu) {
        rr.x = fmaxf(rr.x, 0.f); rr.y = fmaxf(rr.y, 0.f);
        rr.z = fmaxf(rr.z, 0.f); rr.w = fmaxf(rr.w, 0.f);
    }
    *(float4*)(out + (size_t)n * opitch + j) = rr;
}

// bf16 gather aggregate, 2 cols/thread (2|C) — C=50; pitched output
__global__ void aggregate_v2h_kernel(const unsigned short* __restrict__ h16,
                                     const float* __restrict__ alpha_t,
                                     const int* __restrict__ off,
                                     const int* __restrict__ csr_src,
                                     const float* __restrict__ bias,
                                     float* __restrict__ out,
                                     int C, int HC, int HC2, int total2, int opitch) {
    int t = blockIdx.x * blockDim.x + threadIdx.x;
    if (t >= total2) return;
    int n = t / HC2, j2 = t - n * HC2;
    int j = j2 * 2;
    int hd = j / C;
    const float* arow = alpha_t + (size_t)hd * ET;
    int s = off[n], e = off[n + 1];
    float2 acc = make_float2(0.f, 0.f);
    int p = s;
    for (; p + 3 < e; p += 4) {
        int idx[4]; float a[4];
#pragma unroll
        for (int u = 0; u < 4; u++) { idx[u] = csr_src[p + u]; a[u] = arow[p + u]; }
#pragma unroll
        for (int u = 0; u < 4; u++) {
            ushort2 uv = *(const ushort2*)(h16 + (size_t)idx[u] * HC + j);
            acc.x += a[u] * bf2f(uv.x);
            acc.y += a[u] * bf2f(uv.y);
        }
    }
    for (; p < e; p++) {
        int s0 = csr_src[p];
        float a0 = arow[p];
        ushort2 uv = *(const ushort2*)(h16 + (size_t)s0 * HC + j);
        acc.x += a0 * bf2f(uv.x);
        acc.y += a0 * bf2f(uv.y);
    }
    float2 bi = *(const float2*)(bias + j);
    *(float2*)(out + (size_t)n * opitch + j) = make_float2(acc.x + bi.x, acc.y + bi.y);
}

// scalar fallback (layer 5, HC==1)
__global__ void aggregate_kernel(const float* __restrict__ hfeat,
                                 const float* __restrict__ alpha_t,
                                 const int* __restrict__ off, const int* __restrict__ csr_src,
                                 const float* __restrict__ bias, float* __restrict__ out,
                                 int total) {
    int t = blockIdx.x * blockDim.x + threadIdx.x;
    if (t >= total) return;
    int n = t;
    int s = off[n], e = off[n + 1];
    float acc = 0.f;
    int p = s;
    for (; p + 3 < e; p += 4) {
        acc += alpha_t[p] * hfeat[csr_src[p]]
             + alpha_t[p + 1] * hfeat[csr_src[p + 1]]
             + alpha_t[p + 2] * hfeat[csr_src[p + 2]]
             + alpha_t[p + 3] * hfeat[csr_src[p + 3]];
    }
    for (; p < e; p++) acc += alpha_t[p] * hfeat[csr_src[p]];
    out[n] = acc + bias[0];
}

// ---------------- BN stats (pitched); 128 blocks -> 4x fewer column atomics ----------------

__global__ void bn_stats_kernel(const float* __restrict__ x, float* __restrict__ colsum,
                                float* __restrict__ colsumsq, int D, int pitch) {
    int rows_per_block = (NN + gridDim.x - 1) / gridDim.x;
    int r0 = blockIdx.x * rows_per_block;
    int r1 = min(NN, r0 + rows_per_block);
    int c0 = threadIdx.x;
    int c1 = threadIdx.x + 256;
    float s0 = 0.f, q0 = 0.f, s1 = 0.f, q1 = 0.f;
    for (int r = r0; r < r1; r++) {
        const float* row = x + (size_t)r * pitch;
        if (c0 < D) { float v = row[c0]; s0 += v; q0 += v * v; }
        if (c1 < D) { float v = row[c1]; s1 += v; q1 += v * v; }
    }
    if (c0 < D) { atomicAdd(&colsum[c0], s0); atomicAdd(&colsumsq[c0], q0); }
    if (c1 < D) { atomicAdd(&colsum[c1], s1); atomicAdd(&colsumsq[c1], q1); }
}

// ---------------- host orchestration ----------------

static inline size_t align_up(size_t v, size_t a) { return (v + a - 1) / a * a; }

extern "C" void kernel_launch(void* const* d_in, const int* in_sizes, int n_in,
                              void* d_out, int out_size, void* d_ws, size_t ws_size,
                              hipStream_t stream) {
    const float* x_in = (const float*)d_in[0];
    const int* ei     = (const int*)d_in[1];
    const float* ew   = (const float*)d_in[2];

    char* pws = (char*)d_ws;
    size_t off_b = 0;
    auto alloc = [&](size_t bytes) -> void* {
        void* rp = pws + off_b;
        off_b = align_up(off_b + bytes, 256);
        return rp;
    };
    float* B0      = (float*)alloc((size_t)NN * 4);            // l5 h vector
    float* B1      = (float*)alloc((size_t)NN * 512 * 4);      // activations (pitched)
    unsigned short* H16 = (unsigned short*)alloc((size_t)NN * 500 * 2);
    float* alpha_t = (float*)alloc((size_t)ET * 5 * 4);        // [H][ET]
    unsigned short* Wt_hi = (unsigned short*)alloc((size_t)600 * 512 * 2);
    unsigned short* Wt_lo = (unsigned short*)alloc((size_t)600 * 512 * 2);
    float* al_src  = (float*)alloc((size_t)NN * 5 * 4);
    float* al_dst  = (float*)alloc((size_t)NN * 5 * 4);
    float* csr_ea  = (float*)alloc((size_t)ET * 4);
    int* rankb     = (int*)alloc((size_t)ET * 4);
    int* csr_src   = (int*)alloc((size_t)ET * 4);
    int* offarr    = (int*)alloc((size_t)(NN + 1) * 4);
    float* we_dot  = (float*)alloc(40 * 4);
    // zero-region: esum + cnt + 3x colsum + 3x colsumsq (one memset)
    float* esum    = (float*)alloc(4);
    int* cnt       = (int*)alloc((size_t)NN * 4);
    float* colsum_all   = (float*)alloc(3 * 512 * 4);
    float* colsumsq_all = (float*)alloc(3 * 512 * 4);
    char* zero_end = pws + off_b;
    (void)ws_size; (void)n_in; (void)in_sizes; (void)out_size;

    int Kp[5], Np[5];
    size_t wtoff[5];
    size_t acc_off = 0;
    for (int l = 0; l < 5; l++) {
        int K = g_cfg[l].cin, HC = g_cfg[l].C * g_cfg[l].H;
        Kp[l] = (K + 31) / 32 * 32;
        Np[l] = (HC + 127) / 128 * 128;
        wtoff[l] = acc_off;
        acc_off += (size_t)Kp[l] * Np[l];
    }

    PrepArgs pa;
    for (int l = 0; l < 5; l++) {
        pa.W[l]  = (const float*)d_in[3 + l * 6 + 0];
        pa.We[l] = (const float*)d_in[3 + l * 6 + 3];
        pa.ae[l] = (const float*)d_in[3 + l * 6 + 4];
        pa.bh[l] = Wt_hi + wtoff[l];
        pa.bl[l] = Wt_lo + wtoff[l];
        pa.K[l] = g_cfg[l].cin;
        pa.N[l] = g_cfg[l].C * g_cfg[l].H;
        pa.Kp[l] = Kp[l];
        pa.Np[l] = Np[l];
        pa.C[l] = g_cfg[l].C;
        pa.H[l] = g_cfg[l].H;
    }
    pa.wedot = we_dot;

    // graph & CSR build (one atomic pass; fill uses rank -> plain stores)
    hipMemsetAsync(esum, 0, (size_t)(zero_end - (char*)esum), stream);
    int ebl = (ET + 255) / 256;
    ewsum_kernel<<<256, 256, 0, stream>>>(ew, esum);
    build_edges_kernel<<<ebl, 256, 0, stream>>>(ei, rankb, cnt);
    scan_kernel<<<1, 1024, 0, stream>>>(cnt, offarr);
    fill_kernel<<<ebl, 256, 0, stream>>>(ei, rankb, ew, esum, offarr, csr_src, csr_ea);

    // all-layer weight prep (+ wedot fused)
    transpose_all_kernel<<<dim3(16, 16, 5), dim3(32, 8), 0, stream>>>(pa);

    for (int l = 0; l < 5; l++) {
        const LayerCfg& cf = g_cfg[l];
        int H = cf.H, C = cf.C;
        int HC = H * C;
        const float* a_s = (const float*)d_in[3 + l * 6 + 1];
        const float* a_d = (const float*)d_in[3 + l * 6 + 2];
        const float* b   = (const float*)d_in[3 + l * 6 + 5];

        const float* X = (l == 0) ? x_in : B1;
        float* outbuf = (l == 4) ? (float*)d_out : B1;
        int opitch = (l == 4) ? 1 : Kp[l + 1];
        int NH = NN * H;
        int alblocks = (NN * 64 + 255) / 256;

        if (l == 4) {
            gemv_l5_kernel<<<(NN + 255) / 256, 256, 0, stream>>>(
                X, pa.W[4], a_s, a_d, B0, al_src, al_dst);
        } else {
            const float* cs = (l >= 1) ? colsum_all + (l - 1) * 512 : nullptr;
            const float* cq = (l >= 1) ? colsumsq_all + (l - 1) * 512 : nullptr;
            const float* gg = (l >= 1) ? (const float*)d_in[33 + (l - 1) * 2 + 0] : nullptr;
            const float* bb = (l >= 1) ? (const float*)d_in[33 + (l - 1) * 2 + 1] : nullptr;
            int Din = (l >= 1) ? g_cfg[l - 1].C * g_cfg[l - 1].H : 0;
            dim3 ggrid(Np[l] / GBNT, (NN + GBM - 1) / GBM);
            gemm_split_kernel<<<ggrid, 256, 0, stream>>>(X, Wt_hi + wtoff[l], Wt_lo + wtoff[l],
                                                         nullptr, H16,
                                                         NN, Kp[l], HC, cs, cq, gg, bb, Din);
            al_wave_h16_kernel<<<alblocks, 256, 0, stream>>>(H16, a_s, a_d, al_src, al_dst, H, C, HC);
        }

        attn_kernel<<<(NH + 255) / 256, 256, 0, stream>>>(al_src, al_dst, csr_src, csr_ea,
                                                          we_dot + l * 8, offarr, alpha_t, H, NH);

        if (l == 4) {
            aggregate_kernel<<<(NN + 255) / 256, 256, 0, stream>>>(
                B0, alpha_t, offarr, csr_src, b, outbuf, NN);
        } else if ((C & 3) == 0) {
            int HC4 = HC / 4;
            int total4 = NN * HC4;
            aggregate_v4h_kernel<<<(total4 + 255) / 256, 256, 0, stream>>>(
                H16, alpha_t, offarr, csr_src, b, outbuf, C, HC, HC4, total4,
                (l == 3) ? 1 : 0, opitch);
        } else {
            int HC2 = HC / 2;
            int total2 = NN * HC2;
            aggregate_v2h_kernel<<<(total2 + 255) / 256, 256, 0, stream>>>(
                H16, alpha_t, offarr, csr_src, b, outbuf, C, HC, HC2, total2, opitch);
        }

        // BN stats for layers 0..2 (consumed by next layer's GEMM staging)
        if (l < 3) {
            bn_stats_kernel<<<128, 256, 0, stream>>>(outbuf, colsum_all + l * 512,
                                                     colsumsq_all + l * 512, HC, opitch);
        }
    }
}

// Round 20
// 822.964 us; speedup vs baseline: 1.1847x; 1.1847x over previous
//
#include <hip/hip_runtime.h>
#include <hip/hip_bf16.h>
#include <math.h>

// ---------------- problem constants ----------------
#define NN 30000
#define EE 480000
#define ET (EE + NN)   // edges + self loops = 510000
#define NEG_SLOPE 0.2f
#define BN_EPS 1e-5f

struct LayerCfg { int cin, C, H; };
static const LayerCfg g_cfg[5] = {
    {128, 100, 5}, {500, 50, 5}, {250, 32, 4}, {128, 8, 4}, {32, 1, 1}
};

typedef short short8 __attribute__((ext_vector_type(8)));
typedef float f32x4 __attribute__((ext_vector_type(4)));

__device__ __forceinline__ unsigned short f2bf(float f) {
    unsigned int u = __builtin_bit_cast(unsigned int, f);
    u = (u + 0x7FFFu + ((u >> 16) & 1u)) >> 16;
    return (unsigned short)u;
}
__device__ __forceinline__ float bf2f(unsigned short h) {
    unsigned int u = ((unsigned int)h) << 16;
    return __builtin_bit_cast(float, u);
}

// ---------------- graph / CSR kernels ----------------

// standalone edge-weight sum (LDS reduce, 1 atomic per block)
__global__ void ewsum_kernel(const float* __restrict__ ew, float* __restrict__ out) {
    __shared__ float sdata[256];
    int tid = threadIdx.x;
    float s = 0.f;
    for (int i = blockIdx.x * blockDim.x + tid; i < EE; i += gridDim.x * blockDim.x)
        s += ew[i];
    sdata[tid] = s;
    __syncthreads();
    for (int off = 128; off > 0; off >>= 1) {
        if (tid < off) sdata[tid] += sdata[tid + off];
        __syncthreads();
    }
    if (tid == 0) atomicAdd(out, sdata[0]);
}

// per-edge rank via ONE atomic histogram pass (~85us scattered-RMW floor)
__global__ void build_edges_kernel(const int* __restrict__ ei,
                                   int* __restrict__ rank, int* __restrict__ cnt) {
    int e = blockIdx.x * blockDim.x + threadIdx.x;
    if (e >= ET) return;
    int d = (e < EE) ? ei[EE + e] : (e - EE);
    rank[e] = atomicAdd(&cnt[d], 1);
}

// exclusive prefix over cnt -> off; log-step scan over the 1024 partials
__global__ void scan_kernel(const int* __restrict__ cnt, int* __restrict__ off) {
    __shared__ int lsum[1024];
    const int T = 1024;
    int t = threadIdx.x;
    int chunk = (NN + T - 1) / T;
    int base = t * chunk;
    int end = min(NN, base + chunk);
    int s = 0;
    for (int i = base; i < end; i++) s += cnt[i];
    lsum[t] = s;
    __syncthreads();
    for (int d = 1; d < T; d <<= 1) {
        int v = (t >= d) ? lsum[t - d] : 0;
        __syncthreads();
        lsum[t] += v;
        __syncthreads();
    }
    int run = (t == 0) ? 0 : lsum[t - 1];
    for (int i = base; i < end; i++) {
        off[i] = run;
        run += cnt[i];
    }
    if (t == 0) off[NN] = ET;
}

// scatter edges to CSR order via precomputed rank — NO atomics; src/dst from ei
__global__ void fill_kernel(const int* __restrict__ ei, const int* __restrict__ rank,
                            const float* __restrict__ ew, const float* __restrict__ esum,
                            const int* __restrict__ off,
                            int* __restrict__ csr_src, float* __restrict__ csr_ea) {
    int e = blockIdx.x * blockDim.x + threadIdx.x;
    if (e >= ET) return;
    int sv, d;
    if (e < EE) { sv = ei[e]; d = ei[EE + e]; }
    else        { sv = e - EE; d = e - EE; }
    int p = off[d] + rank[e];
    csr_src[p] = sv;
    csr_ea[p]  = (e < EE) ? ew[e] : esum[0] * (1.0f / (float)EE);
}

// ---------------- all-layer weight prep (transpose + wedot fused) ----------------

struct PrepArgs {
    const float* W[5];
    const float* We[5];
    const float* ae[5];
    unsigned short* bh[5];
    unsigned short* bl[5];
    float* wedot;            // out: [5][8]
    int K[5], N[5], Kp[5], Np[5], C[5], H[5];
};

__global__ void transpose_all_kernel(PrepArgs a) {
    int l = blockIdx.z;
    if (blockIdx.x == 0 && blockIdx.y == 0 && threadIdx.y == 0 && threadIdx.x < 8) {
        int hd = threadIdx.x;
        if (hd < a.H[l]) {
            int C = a.C[l];
            const float* We = a.We[l] + hd * C;
            const float* ae = a.ae[l] + hd * C;
            float s = 0.f;
            for (int c = 0; c < C; c++) s += We[c] * ae[c];
            a.wedot[l * 8 + hd] = s;
        }
    }
    int Kp = a.Kp[l], Np = a.Np[l], K = a.K[l], N = a.N[l];
    int kb = blockIdx.x * 32, nb = blockIdx.y * 32;
    if (kb >= Kp || nb >= Np) return;
    const float* B = a.W[l];
    unsigned short* Bth = a.bh[l];
    unsigned short* Btl = a.bl[l];
    __shared__ float tile[32][33];
    int tx = threadIdx.x, ty = threadIdx.y;   // 32 x 8
#pragma unroll
    for (int i = 0; i < 4; i++) {
        int k = kb + ty + i * 8, n = nb + tx;
        tile[ty + i * 8][tx] = (k < K && n < N) ? B[(size_t)k * N + n] : 0.f;
    }
    __syncthreads();
#pragma unroll
    for (int i = 0; i < 4; i++) {
        int n = nb + ty + i * 8, k = kb + tx;
        if (n < Np && k < Kp) {
            float v = tile[tx][ty + i * 8];
            unsigned short hi = f2bf(v);
            unsigned short lo = f2bf(v - bf2f(hi));
            size_t idx = (size_t)n * Kp + k;
            Bth[idx] = hi;
            Btl[idx] = lo;
        }
    }
}

// ---------------- split-bf16 MFMA GEMM with optional fused BN+ReLU on A ----------------
#define GBM 128
#define GBNT 128
#define GBK 32
#define ASTR 36
__global__ __launch_bounds__(256) void gemm_split_kernel(const float* __restrict__ A,
                                                         const unsigned short* __restrict__ Bt_hi,
                                                         const unsigned short* __restrict__ Bt_lo,
                                                         float* __restrict__ Cm,
                                                         unsigned short* __restrict__ Ch16,
                                                         int M, int Kp, int Nc,
                                                         const float* __restrict__ colsum,
                                                         const float* __restrict__ colsumsq,
                                                         const float* __restrict__ g,
                                                         const float* __restrict__ beta,
                                                         int D) {
    __shared__ short AsH[GBM * ASTR];
    __shared__ short AsL[GBM * ASTR];
    __shared__ short BsH[GBNT * ASTR];
    __shared__ short BsL[GBNT * ASTR];
    __shared__ float sscale[512];
    __shared__ float sshift[512];
    int tid = threadIdx.x;
    bool bn = (colsum != nullptr);
    if (bn) {
        for (int c = tid; c < Kp; c += 256) {
            float sc = 0.f, sh = 0.f;
            if (c < D) {
                float mu = colsum[c] * (1.0f / (float)NN);
                float var = colsumsq[c] * (1.0f / (float)NN) - mu * mu;
                sc = g[c] * rsqrtf(var + BN_EPS);
                sh = beta[c] - mu * sc;
            }
            sscale[c] = sc;
            sshift[c] = sh;
        }
        __syncthreads();
    }
    int wave = tid >> 6, lane = tid & 63;
    int q = lane >> 4, r = lane & 15;
    int m0 = blockIdx.y * GBM, n0 = blockIdx.x * GBNT;
    int wm = (wave & 1) * 64, wn = (wave >> 1) * 64;
    f32x4 acc[4][4];
#pragma unroll
    for (int i = 0; i < 4; i++)
#pragma unroll
        for (int j = 0; j < 4; j++) acc[i][j] = (f32x4)(0.f);

    int arow2 = tid >> 1;
    int acol2 = (tid & 1) * 16;
    int brow = tid >> 2;
    int bcol = (tid & 3) * 8;

    int ksteps = Kp / GBK;
    for (int ks = 0; ks < ksteps; ks++) {
        int k0 = ks * GBK;
        {
            int m = m0 + arow2;
            float v[16];
            if (m < M) {
                const float* Ap = A + (size_t)m * Kp + k0 + acol2;
                float4 f0 = *(const float4*)(Ap);
                float4 f1 = *(const float4*)(Ap + 4);
                float4 f2 = *(const float4*)(Ap + 8);
                float4 f3 = *(const float4*)(Ap + 12);
                v[0]=f0.x; v[1]=f0.y; v[2]=f0.z; v[3]=f0.w;
                v[4]=f1.x; v[5]=f1.y; v[6]=f1.z; v[7]=f1.w;
                v[8]=f2.x; v[9]=f2.y; v[10]=f2.z; v[11]=f2.w;
                v[12]=f3.x; v[13]=f3.y; v[14]=f3.z; v[15]=f3.w;
                if (bn) {
                    int cb = k0 + acol2;
#pragma unroll
                    for (int i = 0; i < 16; i++)
                        v[i] = fmaxf(v[i] * sscale[cb + i] + sshift[cb + i], 0.f);
                }
            } else {
#pragma unroll
                for (int i = 0; i < 16; i++) v[i] = 0.f;
            }
#pragma unroll
            for (int i = 0; i < 16; i++) {
                unsigned short hi = f2bf(v[i]);
                unsigned short lo = f2bf(v[i] - bf2f(hi));
                AsH[arow2 * ASTR + acol2 + i] = (short)hi;
                AsL[arow2 * ASTR + acol2 + i] = (short)lo;
            }
        }
#pragma unroll
        for (int p = 0; p < 2; p++) {
            int row = p * 64 + brow;
            size_t gidx = (size_t)(n0 + row) * Kp + k0 + bcol;
            *((uint4*)(BsH + row * ASTR + bcol)) = *((const uint4*)(Bt_hi + gidx));
            *((uint4*)(BsL + row * ASTR + bcol)) = *((const uint4*)(Bt_lo + gidx));
        }
        __syncthreads();
        short8 ah[4], al[4], bh[4], bl[4];
#pragma unroll
        for (int i = 0; i < 4; i++) {
            ah[i] = *((const short8*)(AsH + (wm + i * 16 + r) * ASTR + q * 8));
            al[i] = *((const short8*)(AsL + (wm + i * 16 + r) * ASTR + q * 8));
        }
#pragma unroll
        for (int j = 0; j < 4; j++) {
            bh[j] = *((const short8*)(BsH + (wn + j * 16 + r) * ASTR + q * 8));
            bl[j] = *((const short8*)(BsL + (wn + j * 16 + r) * ASTR + q * 8));
        }
#pragma unroll
        for (int i = 0; i < 4; i++)
#pragma unroll
            for (int j = 0; j < 4; j++) {
                acc[i][j] = __builtin_amdgcn_mfma_f32_16x16x32_bf16(ah[i], bh[j], acc[i][j], 0, 0, 0);
                acc[i][j] = __builtin_amdgcn_mfma_f32_16x16x32_bf16(ah[i], bl[j], acc[i][j], 0, 0, 0);
                acc[i][j] = __builtin_amdgcn_mfma_f32_16x16x32_bf16(al[i], bh[j], acc[i][j], 0, 0, 0);
            }
        __syncthreads();
    }
#pragma unroll
    for (int i = 0; i < 4; i++) {
#pragma unroll
        for (int j = 0; j < 4; j++) {
#pragma unroll
            for (int reg = 0; reg < 4; reg++) {
                int mrow = m0 + wm + i * 16 + q * 4 + reg;
                int ncol = n0 + wn + j * 16 + r;
                if (mrow < M && ncol < Nc) {
                    float val = acc[i][j][reg];
                    if (Cm)   Cm[(size_t)mrow * Nc + ncol] = val;
                    if (Ch16) Ch16[(size_t)mrow * Nc + ncol] = f2bf(val);
                }
            }
        }
    }
}

// layer-5 fused GEMV
__global__ void gemv_l5_kernel(const float* __restrict__ X, const float* __restrict__ W,
                               const float* __restrict__ a_s, const float* __restrict__ a_d,
                               float* __restrict__ h, float* __restrict__ al_src,
                               float* __restrict__ al_dst) {
    __shared__ float w[32];
    if (threadIdx.x < 32) w[threadIdx.x] = W[threadIdx.x];
    __syncthreads();
    int n = blockIdx.x * blockDim.x + threadIdx.x;
    if (n >= NN) return;
    const float* row = X + (size_t)n * 32;
    float s = 0.f;
#pragma unroll
    for (int i = 0; i < 8; i++) {
        float4 f = *(const float4*)(row + i * 4);
        s += f.x * w[i * 4] + f.y * w[i * 4 + 1] + f.z * w[i * 4 + 2] + f.w * w[i * 4 + 3];
    }
    h[n] = s;
    al_src[n] = s * a_s[0];
    al_dst[n] = s * a_d[0];
}

// wave-per-node attention dots, bf16 h (layers 1-4)
__global__ void al_wave_h16_kernel(const unsigned short* __restrict__ h16,
                                   const float* __restrict__ a_s,
                                   const float* __restrict__ a_d,
                                   float* __restrict__ al_src, float* __restrict__ al_dst,
                                   int H, int C, int HC) {
    int w = (blockIdx.x * blockDim.x + threadIdx.x) >> 6;
    int lane = threadIdx.x & 63;
    if (w >= NN) return;
    const unsigned short* row = h16 + (size_t)w * HC;
    float s1[5] = {0.f, 0.f, 0.f, 0.f, 0.f};
    float s2[5] = {0.f, 0.f, 0.f, 0.f, 0.f};
#pragma unroll
    for (int hd = 0; hd < 5; hd++) {
        if (hd >= H) break;
        int base = hd * C;
        for (int c = lane * 2; c < C; c += 128) {
            unsigned int u = *(const unsigned int*)(row + base + c);
            float v0 = bf2f((unsigned short)(u & 0xffffu));
            float v1 = bf2f((unsigned short)(u >> 16));
            s1[hd] += v0 * a_s[base + c] + v1 * a_s[base + c + 1];
            s2[hd] += v0 * a_d[base + c] + v1 * a_d[base + c + 1];
        }
    }
#pragma unroll
    for (int hd = 0; hd < 5; hd++) {
        if (hd >= H) break;
#pragma unroll
        for (int off = 32; off > 0; off >>= 1) {
            s1[hd] += __shfl_xor(s1[hd], off, 64);
            s2[hd] += __shfl_xor(s2[hd], off, 64);
        }
    }
    if (lane == 0) {
#pragma unroll
        for (int hd = 0; hd < 5; hd++) {
            if (hd >= H) break;
            al_src[(size_t)w * H + hd] = s1[hd];
            al_dst[(size_t)w * H + hd] = s2[hd];
        }
    }
}

// fused logit + ONLINE segment softmax; alpha_t[hd*ET + p]
__global__ void attn_kernel(const float* __restrict__ al_src,
                            const float* __restrict__ al_dst,
                            const int* __restrict__ csr_src,
                            const float* __restrict__ csr_ea,
                            const float* __restrict__ we_dot,
                            const int* __restrict__ off,
                            float* __restrict__ alpha_t, int H, int NH) {
    int t = blockIdx.x * blockDim.x + threadIdx.x;
    if (t >= NH) return;
    int n = t / H, hd = t - n * H;
    int s = off[n], e = off[n + 1];
    float ad = al_dst[(size_t)n * H + hd];
    float wd = we_dot[hd];
    float* arow = alpha_t + (size_t)hd * ET;
    float m = -INFINITY, l = 0.f;
    int p = s;
    for (; p + 3 < e; p += 4) {
        int s0 = csr_src[p], s1 = csr_src[p + 1], s2 = csr_src[p + 2], s3 = csr_src[p + 3];
        float w0 = csr_ea[p], w1 = csr_ea[p + 1], w2 = csr_ea[p + 2], w3 = csr_ea[p + 3];
        float l0 = al_src[(size_t)s0 * H + hd] + ad + w0 * wd;
        float l1 = al_src[(size_t)s1 * H + hd] + ad + w1 * wd;
        float l2 = al_src[(size_t)s2 * H + hd] + ad + w2 * wd;
        float l3 = al_src[(size_t)s3 * H + hd] + ad + w3 * wd;
        l0 = (l0 >= 0.f) ? l0 : NEG_SLOPE * l0;
        l1 = (l1 >= 0.f) ? l1 : NEG_SLOPE * l1;
        l2 = (l2 >= 0.f) ? l2 : NEG_SLOPE * l2;
        l3 = (l3 >= 0.f) ? l3 : NEG_SLOPE * l3;
        arow[p] = l0; arow[p + 1] = l1; arow[p + 2] = l2; arow[p + 3] = l3;
        float mq = fmaxf(fmaxf(l0, l1), fmaxf(l2, l3));
        float nm = fmaxf(m, mq);
        l = l * __expf(m - nm)
          + __expf(l0 - nm) + __expf(l1 - nm) + __expf(l2 - nm) + __expf(l3 - nm);
        m = nm;
    }
    for (; p < e; p++) {
        float lg = al_src[(size_t)csr_src[p] * H + hd] + ad + csr_ea[p] * wd;
        lg = (lg >= 0.f) ? lg : NEG_SLOPE * lg;
        arow[p] = lg;
        float nm = fmaxf(m, lg);
        l = l * __expf(m - nm) + __expf(lg - nm);
        m = nm;
    }
    float inv = 1.f / fmaxf(l, 1e-16f);
    for (p = s; p < e; p++) arow[p] = __expf(arow[p] - m) * inv;
}

// bf16 gather aggregate, 4 cols/thread (4|C); optional fused relu; pitched output
__global__ void aggregate_v4h_kernel(const unsigned short* __restrict__ h16,
                                     const float* __restrict__ alpha_t,
                                     const int* __restrict__ off,
                                     const int* __restrict__ csr_src,
                                     const float* __restrict__ bias,
                                     float* __restrict__ out,
                                     int C, int HC, int HC4, int total4, int relu, int opitch) {
    int t = blockIdx.x * blockDim.x + threadIdx.x;
    if (t >= total4) return;
    int n = t / HC4, j4 = t - n * HC4;
    int j = j4 * 4;
    int hd = j / C;
    const float* arow = alpha_t + (size_t)hd * ET;
    int s = off[n], e = off[n + 1];
    float4 acc = make_float4(0.f, 0.f, 0.f, 0.f);
    int p = s;
    for (; p + 3 < e; p += 4) {
        int idx[4]; float a[4];
#pragma unroll
        for (int u = 0; u < 4; u++) { idx[u] = csr_src[p + u]; a[u] = arow[p + u]; }
#pragma unroll
        for (int u = 0; u < 4; u++) {
            ushort4 uv = *(const ushort4*)(h16 + (size_t)idx[u] * HC + j);
            acc.x += a[u] * bf2f(uv.x);
            acc.y += a[u] * bf2f(uv.y);
            acc.z += a[u] * bf2f(uv.z);
            acc.w += a[u] * bf2f(uv.w);
        }
    }
    for (; p < e; p++) {
        int s0 = csr_src[p];
        float a0 = arow[p];
        ushort4 uv = *(const ushort4*)(h16 + (size_t)s0 * HC + j);
        acc.x += a0 * bf2f(uv.x);
        acc.y += a0 * bf2f(uv.y);
        acc.z += a0 * bf2f(uv.z);
        acc.w += a0 * bf2f(uv.w);
    }
    float4 bi = *(const float4*)(bias + j);
    float4 rr = make_float4(acc.x + bi.x, acc.y + bi.y, acc.z + bi.z, acc.w + bi.w);
    if (relu) {
        rr.x = fmaxf(rr.x, 0.f); rr.y = fmaxf(rr.y, 0.f);
        rr.z = fmaxf(rr.z, 0.f); rr.w = fmaxf(rr.w, 0.f);
    }
    *(float4*)(out + (size_t)n * opitch + j) = rr;
}

// bf16 gather aggregate, 2 cols/thread (2|C) — C=50; pitched output
__global__ void aggregate_v2h_kernel(const unsigned short* __restrict__ h16,
                                     const float* __restrict__ alpha_t,
                                     const int* __restrict__ off,
                                     const int* __restrict__ csr_src,
                                     const float* __restrict__ bias,
                                     float* __restrict__ out,
                                     int C, int HC, int HC2, int total2, int opitch) {
    int t = blockIdx.x * blockDim.x + threadIdx.x;
    if (t >= total2) return;
    int n = t / HC2, j2 = t - n * HC2;
    int j = j2 * 2;
    int hd = j / C;
    const float* arow = alpha_t + (size_t)hd * ET;
    int s = off[n], e = off[n + 1];
    float2 acc = make_float2(0.f, 0.f);
    int p = s;
    for (; p + 3 < e; p += 4) {
        int idx[4]; float a[4];
#pragma unroll
        for (int u = 0; u < 4; u++) { idx[u] = csr_src[p + u]; a[u] = arow[p + u]; }
#pragma unroll
        for (int u = 0; u < 4; u++) {
            ushort2 uv = *(const ushort2*)(h16 + (size_t)idx[u] * HC + j);
            acc.x += a[u] * bf2f(uv.x);
            acc.y += a[u] * bf2f(uv.y);
        }
    }
    for (; p < e; p++) {
        int s0 = csr_src[p];
        float a0 = arow[p];
        ushort2 uv = *(const ushort2*)(h16 + (size_t)s0 * HC + j);
        acc.x += a0 * bf2f(uv.x);
        acc.y += a0 * bf2f(uv.y);
    }
    float2 bi = *(const float2*)(bias + j);
    *(float2*)(out + (size_t)n * opitch + j) = make_float2(acc.x + bi.x, acc.y + bi.y);
}

// scalar fallback (layer 5, HC==1)
__global__ void aggregate_kernel(const float* __restrict__ hfeat,
                                 const float* __restrict__ alpha_t,
                                 const int* __restrict__ off, const int* __restrict__ csr_src,
                                 const float* __restrict__ bias, float* __restrict__ out,
                                 int total) {
    int t = blockIdx.x * blockDim.x + threadIdx.x;
    if (t >= total) return;
    int n = t;
    int s = off[n], e = off[n + 1];
    float acc = 0.f;
    int p = s;
    for (; p + 3 < e; p += 4) {
        acc += alpha_t[p] * hfeat[csr_src[p]]
             + alpha_t[p + 1] * hfeat[csr_src[p + 1]]
             + alpha_t[p + 2] * hfeat[csr_src[p + 2]]
             + alpha_t[p + 3] * hfeat[csr_src[p + 3]];
    }
    for (; p < e; p++) acc += alpha_t[p] * hfeat[csr_src[p]];
    out[n] = acc + bias[0];
}

// ---------------- BN stats (pitched); 512 blocks (128 was a 5x regression: latency-bound) ----------------

__global__ void bn_stats_kernel(const float* __restrict__ x, float* __restrict__ colsum,
                                float* __restrict__ colsumsq, int D, int pitch) {
    int rows_per_block = (NN + gridDim.x - 1) / gridDim.x;
    int r0 = blockIdx.x * rows_per_block;
    int r1 = min(NN, r0 + rows_per_block);
    int c0 = threadIdx.x;
    int c1 = threadIdx.x + 256;
    float s0 = 0.f, q0 = 0.f, s1 = 0.f, q1 = 0.f;
    for (int r = r0; r < r1; r++) {
        const float* row = x + (size_t)r * pitch;
        if (c0 < D) { float v = row[c0]; s0 += v; q0 += v * v; }
        if (c1 < D) { float v = row[c1]; s1 += v; q1 += v * v; }
    }
    if (c0 < D) { atomicAdd(&colsum[c0], s0); atomicAdd(&colsumsq[c0], q0); }
    if (c1 < D) { atomicAdd(&colsum[c1], s1); atomicAdd(&colsumsq[c1], q1); }
}

// ---------------- host orchestration ----------------

static inline size_t align_up(size_t v, size_t a) { return (v + a - 1) / a * a; }

extern "C" void kernel_launch(void* const* d_in, const int* in_sizes, int n_in,
                              void* d_out, int out_size, void* d_ws, size_t ws_size,
                              hipStream_t stream) {
    const float* x_in = (const float*)d_in[0];
    const int* ei     = (const int*)d_in[1];
    const float* ew   = (const float*)d_in[2];

    char* pws = (char*)d_ws;
    size_t off_b = 0;
    auto alloc = [&](size_t bytes) -> void* {
        void* rp = pws + off_b;
        off_b = align_up(off_b + bytes, 256);
        return rp;
    };
    float* B0      = (float*)alloc((size_t)NN * 4);            // l5 h vector
    float* B1      = (float*)alloc((size_t)NN * 512 * 4);      // activations (pitched)
    unsigned short* H16 = (unsigned short*)alloc((size_t)NN * 500 * 2);
    float* alpha_t = (float*)alloc((size_t)ET * 5 * 4);        // [H][ET]
    unsigned short* Wt_hi = (unsigned short*)alloc((size_t)600 * 512 * 2);
    unsigned short* Wt_lo = (unsigned short*)alloc((size_t)600 * 512 * 2);
    float* al_src  = (float*)alloc((size_t)NN * 5 * 4);
    float* al_dst  = (float*)alloc((size_t)NN * 5 * 4);
    float* csr_ea  = (float*)alloc((size_t)ET * 4);
    int* rankb     = (int*)alloc((size_t)ET * 4);
    int* csr_src   = (int*)alloc((size_t)ET * 4);
    int* offarr    = (int*)alloc((size_t)(NN + 1) * 4);
    float* we_dot  = (float*)alloc(40 * 4);
    // zero-region: esum + cnt + 3x colsum + 3x colsumsq (one memset)
    float* esum    = (float*)alloc(4);
    int* cnt       = (int*)alloc((size_t)NN * 4);
    float* colsum_all   = (float*)alloc(3 * 512 * 4);
    float* colsumsq_all = (float*)alloc(3 * 512 * 4);
    char* zero_end = pws + off_b;
    (void)ws_size; (void)n_in; (void)in_sizes; (void)out_size;

    int Kp[5], Np[5];
    size_t wtoff[5];
    size_t acc_off = 0;
    for (int l = 0; l < 5; l++) {
        int K = g_cfg[l].cin, HC = g_cfg[l].C * g_cfg[l].H;
        Kp[l] = (K + 31) / 32 * 32;
        Np[l] = (HC + 127) / 128 * 128;
        wtoff[l] = acc_off;
        acc_off += (size_t)Kp[l] * Np[l];
    }

    PrepArgs pa;
    for (int l = 0; l < 5; l++) {
        pa.W[l]  = (const float*)d_in[3 + l * 6 + 0];
        pa.We[l] = (const float*)d_in[3 + l * 6 + 3];
        pa.ae[l] = (const float*)d_in[3 + l * 6 + 4];
        pa.bh[l] = Wt_hi + wtoff[l];
        pa.bl[l] = Wt_lo + wtoff[l];
        pa.K[l] = g_cfg[l].cin;
        pa.N[l] = g_cfg[l].C * g_cfg[l].H;
        pa.Kp[l] = Kp[l];
        pa.Np[l] = Np[l];
        pa.C[l] = g_cfg[l].C;
        pa.H[l] = g_cfg[l].H;
    }
    pa.wedot = we_dot;

    // graph & CSR build (one atomic pass; fill uses rank -> plain stores)
    hipMemsetAsync(esum, 0, (size_t)(zero_end - (char*)esum), stream);
    int ebl = (ET + 255) / 256;
    ewsum_kernel<<<256, 256, 0, stream>>>(ew, esum);
    build_edges_kernel<<<ebl, 256, 0, stream>>>(ei, rankb, cnt);
    scan_kernel<<<1, 1024, 0, stream>>>(cnt, offarr);
    fill_kernel<<<ebl, 256, 0, stream>>>(ei, rankb, ew, esum, offarr, csr_src, csr_ea);

    // all-layer weight prep (+ wedot fused)
    transpose_all_kernel<<<dim3(16, 16, 5), dim3(32, 8), 0, stream>>>(pa);

    for (int l = 0; l < 5; l++) {
        const LayerCfg& cf = g_cfg[l];
        int H = cf.H, C = cf.C;
        int HC = H * C;
        const float* a_s = (const float*)d_in[3 + l * 6 + 1];
        const float* a_d = (const float*)d_in[3 + l * 6 + 2];
        const float* b   = (const float*)d_in[3 + l * 6 + 5];

        const float* X = (l == 0) ? x_in : B1;
        float* outbuf = (l == 4) ? (float*)d_out : B1;
        int opitch = (l == 4) ? 1 : Kp[l + 1];
        int NH = NN * H;
        int alblocks = (NN * 64 + 255) / 256;

        if (l == 4) {
            gemv_l5_kernel<<<(NN + 255) / 256, 256, 0, stream>>>(
                X, pa.W[4], a_s, a_d, B0, al_src, al_dst);
        } else {
            const float* cs = (l >= 1) ? colsum_all + (l - 1) * 512 : nullptr;
            const float* cq = (l >= 1) ? colsumsq_all + (l - 1) * 512 : nullptr;
            const float* gg = (l >= 1) ? (const float*)d_in[33 + (l - 1) * 2 + 0] : nullptr;
            const float* bb = (l >= 1) ? (const float*)d_in[33 + (l - 1) * 2 + 1] : nullptr;
            int Din = (l >= 1) ? g_cfg[l - 1].C * g_cfg[l - 1].H : 0;
            dim3 ggrid(Np[l] / GBNT, (NN + GBM - 1) / GBM);
            gemm_split_kernel<<<ggrid, 256, 0, stream>>>(X, Wt_hi + wtoff[l], Wt_lo + wtoff[l],
                                                         nullptr, H16,
                                                         NN, Kp[l], HC, cs, cq, gg, bb, Din);
            al_wave_h16_kernel<<<alblocks, 256, 0, stream>>>(H16, a_s, a_d, al_src, al_dst, H, C, HC);
        }

        attn_kernel<<<(NH + 255) / 256, 256, 0, stream>>>(al_src, al_dst, csr_src, csr_ea,
                                                          we_dot + l * 8, offarr, alpha_t, H, NH);

        if (l == 4) {
            aggregate_kernel<<<(NN + 255) / 256, 256, 0, stream>>>(
                B0, alpha_t, offarr, csr_src, b, outbuf, NN);
        } else if ((C & 3) == 0) {
            int HC4 = HC / 4;
            int total4 = NN * HC4;
            aggregate_v4h_kernel<<<(total4 + 255) / 256, 256, 0, stream>>>(
                H16, alpha_t, offarr, csr_src, b, outbuf, C, HC, HC4, total4,
                (l == 3) ? 1 : 0, opitch);
        } else {
            int HC2 = HC / 2;
            int total2 = NN * HC2;
            aggregate_v2h_kernel<<<(total2 + 255) / 256, 256, 0, stream>>>(
                H16, alpha_t, offarr, csr_src, b, outbuf, C, HC, HC2, total2, opitch);
        }

        // BN stats for layers 0..2 (consumed by next layer's GEMM staging)
        if (l < 3) {
            bn_stats_kernel<<<512, 256, 0, stream>>>(outbuf, colsum_all + l * 512,
                                                     colsumsq_all + l * 512, HC, opitch);
        }
    }
}